// Round 7
// baseline (564.036 us; speedup 1.0000x reference)
//
#include <hip/hip_runtime.h>
#include <hip/hip_bf16.h>

#define LRELU_ALPHA 0.2f

typedef __attribute__((ext_vector_type(8))) __bf16 bf16x8;
typedef __attribute__((ext_vector_type(4))) float f32x4;
typedef __attribute__((ext_vector_type(8))) unsigned short u16x8;
typedef __attribute__((ext_vector_type(4))) unsigned short u16x4;

__device__ __forceinline__ unsigned short f2bf(float f) {
  unsigned int u = __float_as_uint(f);
  u += 0x7fffu + ((u >> 16) & 1u);   // round-to-nearest-even
  return (unsigned short)(u >> 16);
}

__device__ __forceinline__ void gload16(const void* g, void* l) {
  __builtin_amdgcn_global_load_lds(
      (const __attribute__((address_space(1))) void*)g,
      (__attribute__((address_space(3))) void*)l, 16, 0, 0);
}

// ---------------- adj bit-pack: bits[i][w] = 32 adjacency bits ----------------
__global__ __launch_bounds__(256) void pack_adj_k(
    const int* __restrict__ adj, unsigned* __restrict__ bits)
{
  size_t i = blockIdx.x;
  const int* arow = adj + i * 8192;
  unsigned* brow = bits + i * 256;
  int t = threadIdx.x;
  int l = t & 63;
#pragma unroll
  for (int it = 0; it < 32; ++it) {
    int j = it * 256 + t;
    unsigned long long m = __ballot(arow[j] > 0);
    if (l == 0) brow[j >> 5] = (unsigned)m;
    else if (l == 32) brow[j >> 5] = (unsigned)(m >> 32);
  }
}

// ---------------- fp32 tiled GEMM: wh1 = x @ W1 ----------------
__global__ __launch_bounds__(256) void gemm_f32_k(
    const float* __restrict__ A, const float* __restrict__ B,
    float* __restrict__ C, int M, int K, int Ncols)
{
  __shared__ float As[128][17];
  __shared__ float Bs[16][65];
  int t = threadIdx.x;
  int row0 = blockIdx.x * 128;
  int col0 = blockIdx.y * 64;
  int ty = t >> 4, tx = t & 15;
  float acc[8][4];
#pragma unroll
  for (int i = 0; i < 8; ++i)
#pragma unroll
    for (int j = 0; j < 4; ++j) acc[i][j] = 0.f;

  for (int kt = 0; kt < K; kt += 16) {
    __syncthreads();
    {
      int r = t >> 1, h = t & 1;
      const float4* src = (const float4*)(A + (size_t)(row0 + r) * K + kt + h * 8);
      float4 v0 = src[0], v1 = src[1];
      float* dst = &As[r][h * 8];
      dst[0]=v0.x; dst[1]=v0.y; dst[2]=v0.z; dst[3]=v0.w;
      dst[4]=v1.x; dst[5]=v1.y; dst[6]=v1.z; dst[7]=v1.w;
    }
    {
      int kr = t >> 4, seg = t & 15;
      const float4* src = (const float4*)(B + (size_t)(kt + kr) * Ncols + col0 + seg * 4);
      float4 v = src[0];
      float* dst = &Bs[kr][seg * 4];
      dst[0]=v.x; dst[1]=v.y; dst[2]=v.z; dst[3]=v.w;
    }
    __syncthreads();
#pragma unroll
    for (int k = 0; k < 16; ++k) {
      float bb[4];
#pragma unroll
      for (int j = 0; j < 4; ++j) bb[j] = Bs[k][tx * 4 + j];
#pragma unroll
      for (int i = 0; i < 8; ++i) {
        float aa = As[ty * 8 + i][k];
#pragma unroll
        for (int j = 0; j < 4; ++j) acc[i][j] = fmaf(aa, bb[j], acc[i][j]);
      }
    }
  }
#pragma unroll
  for (int i = 0; i < 8; ++i) {
    float4 v = make_float4(acc[i][0], acc[i][1], acc[i][2], acc[i][3]);
    *(float4*)(C + (size_t)(row0 + ty * 8 + i) * Ncols + col0 + tx * 4) = v;
  }
}

// ---------------- e1/e2 vectors: wave per row ----------------
__global__ __launch_bounds__(256) void calc_e_k(
    const float* __restrict__ Wh, const float* __restrict__ a,
    float* __restrict__ e1, float* __restrict__ e2, int F)
{
  int row = blockIdx.x * 4 + (threadIdx.x >> 6);
  int l = threadIdx.x & 63;
  const float* r = Wh + (size_t)row * F;
  float s1 = 0.f, s2 = 0.f;
  for (int f = l; f < F; f += 64) {
    float v = r[f];
    s1 += v * a[f];
    s2 += v * a[F + f];
  }
#pragma unroll
  for (int off = 32; off; off >>= 1) {
    s1 += __shfl_down(s1, off);
    s2 += __shfl_down(s2, off);
  }
  if (l == 0) { e1[row] = s1; e2[row] = s2; }
}

// ---------------- transpose + fp32->bf16: out[c][r] = bf16(in[r][c]) ----------------
__global__ void transpose_bf16_k(const float* __restrict__ in, unsigned short* __restrict__ out,
                                 int R, int Cc)
{
  __shared__ float tile[32][33];
  int tx = threadIdx.x, ty = threadIdx.y;
  int c0 = blockIdx.x * 32, r0 = blockIdx.y * 32;
  int c = c0 + tx;
  if (c < Cc) {
    for (int i = ty; i < 32; i += 8)
      tile[i][tx] = in[(size_t)(r0 + i) * Cc + c];
  }
  __syncthreads();
  int r = r0 + tx;
  for (int i = ty; i < 32; i += 8) {
    int cc = c0 + i;
    if (cc < Cc)
      out[(size_t)cc * R + r] = f2bf(tile[tx][i]);
  }
}

// ---------------- masked row softmax (bits mask): one block per row ----------------
// No max-shift (masked entries exact 0.0; |e|<=~14 so exp fp32-safe; shift-
// invariant — numerics verified identical rounds 3-6). DUAL=1 additionally
// writes a bf16 shadow of the row for the MFMA aggregate's A operand.
template<int DUAL>
__global__ __launch_bounds__(256) void att_softmax_k(
    const unsigned* __restrict__ bits, const float* __restrict__ e1,
    const float* __restrict__ e2, float* __restrict__ att,
    unsigned short* __restrict__ attb)
{
  __shared__ unsigned bw[256];
  __shared__ float red[4];
  int i = blockIdx.x, t = threadIdx.x;
  bw[t] = bits[(size_t)i * 256 + t];
  float e1i = e1[i];
  __syncthreads();
  float4 vv[8];
  float s = 0.f;
#pragma unroll
  for (int it = 0; it < 8; ++it) {
    int j4 = t + it * 256;               // float4 index
    float4 ev = *(const float4*)(e2 + j4 * 4);
    unsigned wb = bw[j4 >> 3];
    int b0 = (j4 & 7) * 4;
    float e, p0, p1, p2, p3;
    e = e1i + ev.x; e = e > 0.f ? e : LRELU_ALPHA * e; p0 = ((wb >> (b0 + 0)) & 1) ? __expf(e) : 0.f;
    e = e1i + ev.y; e = e > 0.f ? e : LRELU_ALPHA * e; p1 = ((wb >> (b0 + 1)) & 1) ? __expf(e) : 0.f;
    e = e1i + ev.z; e = e > 0.f ? e : LRELU_ALPHA * e; p2 = ((wb >> (b0 + 2)) & 1) ? __expf(e) : 0.f;
    e = e1i + ev.w; e = e > 0.f ? e : LRELU_ALPHA * e; p3 = ((wb >> (b0 + 3)) & 1) ? __expf(e) : 0.f;
    vv[it] = make_float4(p0, p1, p2, p3);
    s += (p0 + p1) + (p2 + p3);
  }
#pragma unroll
  for (int off = 32; off; off >>= 1) s += __shfl_xor(s, off);
  if ((t & 63) == 0) red[t >> 6] = s;
  __syncthreads();
  s = red[0] + red[1] + red[2] + red[3];
  float inv = 1.f / s;
  float4* orow = (float4*)(att + (size_t)i * 8192);
  unsigned short* obrow = attb + (size_t)i * 8192;
#pragma unroll
  for (int it = 0; it < 8; ++it) {
    int j4 = t + it * 256;
    float4 p = vv[it];
    p.x *= inv; p.y *= inv; p.z *= inv; p.w *= inv;
    orow[j4] = p;
    if (DUAL) {
      u16x4 b;
      b[0] = f2bf(p.x); b[1] = f2bf(p.y); b[2] = f2bf(p.z); b[3] = f2bf(p.w);
      *(u16x4*)(obrow + j4 * 4) = b;
    }
  }
}

// ---------------- m97-style MFMA GEMM: h1 = ELU(att1b @ bt1^T) ----------------
// BM=128, BN=64, BK=64, 512 thr (8 waves, 4x2), linear LDS, global_load_lds
// width-16 staging, 2-barrier loop. Grid dim3(64,4): bid = bx + 64*by, 64%8==0
// -> the 4 col-blocks of one A row-panel share an XCD -> A panel L2-resident.
__global__ __launch_bounds__(512) void gemm_bt_k(
    const unsigned short* __restrict__ A,    // [8192][8192] bf16
    const unsigned short* __restrict__ BT,   // [256][8192] bf16
    float* __restrict__ C)                   // h1 [8192][256]
{
  __shared__ __align__(16) unsigned short As[128 * 64];   // 16 KB, row = 64 bf16
  __shared__ __align__(16) unsigned short Bs[64 * 64];    //  8 KB
  int t = threadIdx.x;
  int l = t & 63, w = t >> 6;            // 8 waves
  int row0 = blockIdx.x * 128;
  int col0 = blockIdx.y * 64;
  int wm = w >> 1, wn = w & 1;           // wave tile 32x32

  f32x4 acc[2][2] = {};

  // staging: A = 16 chunks of 1KB (8 rows); wave w owns chunks 2w, 2w+1.
  // B = 8 chunks; wave w owns chunk w. lane l -> row +(l>>3), col (l&7)*8.
  const unsigned short* ga0 = A + (size_t)(row0 + 16 * w + (l >> 3)) * 8192 + (l & 7) * 8;
  const unsigned short* ga1 = ga0 + 8 * 8192;
  const unsigned short* gb  = BT + (size_t)(col0 + 8 * w + (l >> 3)) * 8192 + (l & 7) * 8;
  unsigned short* la0 = As + 2 * w * 512 + l * 8;
  unsigned short* la1 = la0 + 512;
  unsigned short* lb  = Bs + w * 512 + l * 8;

  for (int kt = 0; kt < 128; ++kt) {
    __syncthreads();
    gload16(ga0 + kt * 64, la0);
    gload16(ga1 + kt * 64, la1);
    gload16(gb  + kt * 64, lb);
    __syncthreads();   // compiler drains vmcnt before barrier -> LDS valid
#pragma unroll
    for (int kk = 0; kk < 64; kk += 32) {
      int kb = kk + (l >> 4) * 8;
      bf16x8 af[2], bf[2];
#pragma unroll
      for (int fm = 0; fm < 2; ++fm)
        af[fm] = *(const bf16x8*)(As + (wm * 32 + fm * 16 + (l & 15)) * 64 + kb);
#pragma unroll
      for (int fn = 0; fn < 2; ++fn)
        bf[fn] = *(const bf16x8*)(Bs + (wn * 32 + fn * 16 + (l & 15)) * 64 + kb);
#pragma unroll
      for (int fm = 0; fm < 2; ++fm)
#pragma unroll
        for (int fn = 0; fn < 2; ++fn)
          acc[fm][fn] = __builtin_amdgcn_mfma_f32_16x16x32_bf16(af[fm], bf[fn], acc[fm][fn], 0, 0, 0);
    }
  }
  // epilogue: ELU; C/D layout col=lane&15, row=(lane>>4)*4+reg
#pragma unroll
  for (int fm = 0; fm < 2; ++fm) {
#pragma unroll
    for (int fn = 0; fn < 2; ++fn) {
#pragma unroll
      for (int r = 0; r < 4; ++r) {
        int grow = row0 + wm * 32 + fm * 16 + (l >> 4) * 4 + r;
        int gcol = col0 + wn * 32 + fn * 16 + (l & 15);
        float v = acc[fm][fn][r];
        v = v > 0.f ? v : expm1f(v);
        C[(size_t)grow * 256 + gcol] = v;
      }
    }
  }
}

// ---------------- MFMA bf16 GEMM (layer 2): part[z] = att2_f32 @ bt2^T ----------------
// R1-verbatim body: BM=64, BN=16, 4 waves, fp32 A with f2bf staging, split-K.
template<int BN, int SPLITK, int EPI>
__global__ __launch_bounds__(256) void gemm_mfma_k(
    const float* __restrict__ A, const unsigned short* __restrict__ BT,
    float* __restrict__ Cout, int M, int K, int ldc)
{
  constexpr int BM = 64, BK = 64;
  constexpr int WN = (BN == 64) ? 2 : 1;
  constexpr int WM = 4 / WN;
  constexpr int WROWS = BM / WM;
  constexpr int WCOLS = BN / WN;
  constexpr int FM = WROWS / 16;
  constexpr int FN = WCOLS / 16;
  __shared__ __align__(16) char As[BM * BK * 2];
  __shared__ __align__(16) char Bs[BN * BK * 2];
  int t = threadIdx.x;
  int row0 = blockIdx.x * BM;
  int col0 = blockIdx.y * BN;
  int ktiles = K / BK;
  int kt0 = blockIdx.z * (ktiles / SPLITK);
  int kt1 = kt0 + ktiles / SPLITK;
  int w = t >> 6, l = t & 63;
  int wm = w / WN, wn = w % WN;

  f32x4 acc[FM][FN] = {};

  int ar = t >> 2, aseg = t & 3;
  int swzA = (ar & 7) << 4;

  for (int kt = kt0; kt < kt1; ++kt) {
    __syncthreads();
    {
      const float4* src = (const float4*)(A + (size_t)(row0 + ar) * K + kt * BK + aseg * 16);
      float4 v0 = src[0], v1 = src[1], v2 = src[2], v3 = src[3];
      u16x8 c0, c1;
      c0[0]=f2bf(v0.x); c0[1]=f2bf(v0.y); c0[2]=f2bf(v0.z); c0[3]=f2bf(v0.w);
      c0[4]=f2bf(v1.x); c0[5]=f2bf(v1.y); c0[6]=f2bf(v1.z); c0[7]=f2bf(v1.w);
      c1[0]=f2bf(v2.x); c1[1]=f2bf(v2.y); c1[2]=f2bf(v2.z); c1[3]=f2bf(v2.w);
      c1[4]=f2bf(v3.x); c1[5]=f2bf(v3.y); c1[6]=f2bf(v3.z); c1[7]=f2bf(v3.w);
      int base = ar * 128 + aseg * 32;
      *(u16x8*)(As + ((base) ^ swzA)) = c0;
      *(u16x8*)(As + ((base + 16) ^ swzA)) = c1;
    }
    if (BN == 64) {
      int br = t >> 2, seg = t & 3;
      const u16x8* src = (const u16x8*)(BT + (size_t)(col0 + br) * K + kt * BK + seg * 16);
      u16x8 b0 = src[0], b1 = src[1];
      int base = br * 128 + seg * 32;
      int swz = (br & 7) << 4;
      *(u16x8*)(Bs + ((base) ^ swz)) = b0;
      *(u16x8*)(Bs + ((base + 16) ^ swz)) = b1;
    } else {
      int br = t >> 4, seg = t & 15;
      const u16x4* src = (const u16x4*)(BT + (size_t)(col0 + br) * K + kt * BK + seg * 4);
      u16x4 b0 = src[0];
      int base = br * 128 + seg * 8;
      int swz = (br & 7) << 4;
      *(u16x4*)(Bs + (base ^ swz)) = b0;
    }
    __syncthreads();
#pragma unroll
    for (int kk = 0; kk < BK; kk += 32) {
      bf16x8 af[FM], bfr[FN];
      int kb = (kk + (l >> 4) * 8) * 2;
#pragma unroll
      for (int fm = 0; fm < FM; ++fm) {
        int r = wm * WROWS + fm * 16 + (l & 15);
        af[fm] = *(const bf16x8*)(As + ((r * 128 + kb) ^ ((r & 7) << 4)));
      }
#pragma unroll
      for (int fn = 0; fn < FN; ++fn) {
        int c = wn * WCOLS + fn * 16 + (l & 15);
        bfr[fn] = *(const bf16x8*)(Bs + ((c * 128 + kb) ^ ((c & 7) << 4)));
      }
#pragma unroll
      for (int fm = 0; fm < FM; ++fm)
#pragma unroll
        for (int fn = 0; fn < FN; ++fn)
          acc[fm][fn] = __builtin_amdgcn_mfma_f32_16x16x32_bf16(af[fm], bfr[fn], acc[fm][fn], 0, 0, 0);
    }
  }
#pragma unroll
  for (int fm = 0; fm < FM; ++fm) {
#pragma unroll
    for (int fn = 0; fn < FN; ++fn) {
#pragma unroll
      for (int r = 0; r < 4; ++r) {
        int grow = row0 + wm * WROWS + fm * 16 + (l >> 4) * 4 + r;
        int gcol = col0 + wn * WCOLS + fn * 16 + (l & 15);
        float v = acc[fm][fn][r];
        if (EPI == 1) v = v > 0.f ? v : expm1f(v);
        size_t idx = (SPLITK > 1)
          ? ((size_t)blockIdx.z * M + grow) * ldc + gcol
          : (size_t)grow * ldc + gcol;
        Cout[idx] = v;
      }
    }
  }
}

// ---------------- small GEMM: Wh2[M][16] = h1[M][256] @ W2[256][16] ----------------
__global__ __launch_bounds__(256) void gemm_small_k(
    const float* __restrict__ A, const float* __restrict__ B,
    float* __restrict__ C, int K, int Ncols)
{
  int t = threadIdx.x;
  int r = blockIdx.x * 16 + (t >> 4);
  int c = t & 15;
  const float* arow = A + (size_t)r * K;
  float acc = 0.f;
#pragma unroll 8
  for (int k = 0; k < K; ++k)
    acc = fmaf(arow[k], B[k * Ncols + c], acc);
  C[(size_t)r * Ncols + c] = acc;
}

// ---------------- split-K reduce + sigmoid ----------------
__global__ void reduce_sig_k(const float* __restrict__ part, float* __restrict__ out, int total)
{
  int i = blockIdx.x * 256 + threadIdx.x;
  if (i < total) {
    float s = part[i] + part[total + i] + part[2 * (size_t)total + i] + part[3 * (size_t)total + i];
    out[i] = 1.f / (1.f + __expf(-s));
  }
}

extern "C" void kernel_launch(void* const* d_in, const int* in_sizes, int n_in,
                              void* d_out, int out_size, void* d_ws, size_t ws_size,
                              hipStream_t stream)
{
  const float* x   = (const float*)d_in[0];
  const int*   adj = (const int*)d_in[1];
  const float* W1  = (const float*)d_in[2];
  const float* a1  = (const float*)d_in[3];
  const float* W2  = (const float*)d_in[4];
  const float* a2  = (const float*)d_in[5];

  float* out  = (float*)d_out;                 // [8192*16]
  float* h1   = out + 131072;                  // [8192*256]
  float* att1 = h1 + 2097152;                  // [8192*8192]
  float* att2 = att1 + 67108864;               // [8192*8192]

  float* ws = (float*)d_ws;
  float* wh1 = ws;                                            // 2097152 f
  unsigned short* bt1 = (unsigned short*)(wh1 + 2097152);     // 2097152 u16
  float* e1a = wh1 + 2097152 + 1048576;
  float* e2a = e1a + 8192;
  float* wh2 = e2a + 8192;                                    // 131072 f
  unsigned short* bt2 = (unsigned short*)(wh2 + 131072);      // 131072 u16
  float* e1b = wh2 + 131072 + 65536;
  float* e2b = e1b + 8192;
  float* part = e2b + 8192;                                   // 524288 f
  unsigned* bits = (unsigned*)(part + 524288);                // 2097152 u32
  unsigned short* att1b = (unsigned short*)(bits + 2097152);  // 67108864 u16

  pack_adj_k<<<8192, 256, 0, stream>>>(adj, bits);

  // ---- layer 1 ----
  gemm_f32_k<<<dim3(64, 4), 256, 0, stream>>>(x, W1, wh1, 8192, 512, 256);
  calc_e_k<<<2048, 256, 0, stream>>>(wh1, a1, e1a, e2a, 256);
  transpose_bf16_k<<<dim3(8, 256), dim3(32, 8), 0, stream>>>(wh1, bt1, 8192, 256);
  att_softmax_k<1><<<8192, 256, 0, stream>>>(bits, e1a, e2a, att1, att1b);
  gemm_bt_k<<<dim3(64, 4), 512, 0, stream>>>(att1b, bt1, h1);

  // ---- layer 2 ----
  gemm_small_k<<<512, 256, 0, stream>>>(h1, W2, wh2, 256, 16);
  calc_e_k<<<2048, 256, 0, stream>>>(wh2, a2, e1b, e2b, 16);
  transpose_bf16_k<<<dim3(1, 256), dim3(32, 8), 0, stream>>>(wh2, bt2, 8192, 16);
  att_softmax_k<0><<<8192, 256, 0, stream>>>(bits, e1b, e2b, att2, att1b);
  gemm_mfma_k<16, 4, 0><<<dim3(128, 1, 4), 256, 0, stream>>>(att2, bt2, part, 8192, 8192, 16);
  reduce_sig_k<<<512, 256, 0, stream>>>(part, out, 131072);
}

// Round 8
// 493.998 us; speedup vs baseline: 1.1418x; 1.1418x over previous
//
#include <hip/hip_runtime.h>
#include <hip/hip_bf16.h>

#define LRELU_ALPHA 0.2f

typedef __attribute__((ext_vector_type(8))) __bf16 bf16x8;
typedef __attribute__((ext_vector_type(4))) float f32x4;
typedef __attribute__((ext_vector_type(8))) unsigned short u16x8;
typedef __attribute__((ext_vector_type(4))) unsigned short u16x4;

__device__ __forceinline__ unsigned short f2bf(float f) {
  unsigned int u = __float_as_uint(f);
  u += 0x7fffu + ((u >> 16) & 1u);   // round-to-nearest-even
  return (unsigned short)(u >> 16);
}

// ---------------- fp32 tiled GEMM: wh1 = x @ W1 ----------------
__global__ __launch_bounds__(256) void gemm_f32_k(
    const float* __restrict__ A, const float* __restrict__ B,
    float* __restrict__ C, int M, int K, int Ncols)
{
  __shared__ float As[128][17];
  __shared__ float Bs[16][65];
  int t = threadIdx.x;
  int row0 = blockIdx.x * 128;
  int col0 = blockIdx.y * 64;
  int ty = t >> 4, tx = t & 15;
  float acc[8][4];
#pragma unroll
  for (int i = 0; i < 8; ++i)
#pragma unroll
    for (int j = 0; j < 4; ++j) acc[i][j] = 0.f;

  for (int kt = 0; kt < K; kt += 16) {
    __syncthreads();
    {
      int r = t >> 1, h = t & 1;
      const float4* src = (const float4*)(A + (size_t)(row0 + r) * K + kt + h * 8);
      float4 v0 = src[0], v1 = src[1];
      float* dst = &As[r][h * 8];
      dst[0]=v0.x; dst[1]=v0.y; dst[2]=v0.z; dst[3]=v0.w;
      dst[4]=v1.x; dst[5]=v1.y; dst[6]=v1.z; dst[7]=v1.w;
    }
    {
      int kr = t >> 4, seg = t & 15;
      const float4* src = (const float4*)(B + (size_t)(kt + kr) * Ncols + col0 + seg * 4);
      float4 v = src[0];
      float* dst = &Bs[kr][seg * 4];
      dst[0]=v.x; dst[1]=v.y; dst[2]=v.z; dst[3]=v.w;
    }
    __syncthreads();
#pragma unroll
    for (int k = 0; k < 16; ++k) {
      float bb[4];
#pragma unroll
      for (int j = 0; j < 4; ++j) bb[j] = Bs[k][tx * 4 + j];
#pragma unroll
      for (int i = 0; i < 8; ++i) {
        float aa = As[ty * 8 + i][k];
#pragma unroll
        for (int j = 0; j < 4; ++j) acc[i][j] = fmaf(aa, bb[j], acc[i][j]);
      }
    }
  }
#pragma unroll
  for (int i = 0; i < 8; ++i) {
    float4 v = make_float4(acc[i][0], acc[i][1], acc[i][2], acc[i][3]);
    *(float4*)(C + (size_t)(row0 + ty * 8 + i) * Ncols + col0 + tx * 4) = v;
  }
}

// ---------------- e1/e2 vectors: wave per row ----------------
__global__ __launch_bounds__(256) void calc_e_k(
    const float* __restrict__ Wh, const float* __restrict__ a,
    float* __restrict__ e1, float* __restrict__ e2, int F)
{
  int row = blockIdx.x * 4 + (threadIdx.x >> 6);
  int l = threadIdx.x & 63;
  const float* r = Wh + (size_t)row * F;
  float s1 = 0.f, s2 = 0.f;
  for (int f = l; f < F; f += 64) {
    float v = r[f];
    s1 += v * a[f];
    s2 += v * a[F + f];
  }
#pragma unroll
  for (int off = 32; off; off >>= 1) {
    s1 += __shfl_down(s1, off);
    s2 += __shfl_down(s2, off);
  }
  if (l == 0) { e1[row] = s1; e2[row] = s2; }
}

// ---------------- transpose + fp32->bf16: out[c][r] = bf16(in[r][c]) ----------------
__global__ void transpose_bf16_k(const float* __restrict__ in, unsigned short* __restrict__ out,
                                 int R, int Cc)
{
  __shared__ float tile[32][33];
  int tx = threadIdx.x, ty = threadIdx.y;
  int c0 = blockIdx.x * 32, r0 = blockIdx.y * 32;
  int c = c0 + tx;
  if (c < Cc) {
    for (int i = ty; i < 32; i += 8)
      tile[i][tx] = in[(size_t)(r0 + i) * Cc + c];
  }
  __syncthreads();
  int r = r0 + tx;
  for (int i = ty; i < 32; i += 8) {
    int cc = c0 + i;
    if (cc < Cc)
      out[(size_t)cc * R + r] = f2bf(tile[tx][i]);
  }
}

// ---------------- layer-1 masked softmax + inline adj bit-pack ----------------
// One block per row. int4 adj reads, float4 att stores, single-pass (no
// max-shift: masked entries exact 0.0; |e|<=~14 so exp fp32-safe; softmax
// shift-invariant — verified identical numerics rounds 3-7). Packs the
// adjacency bits for this row (8 MB total) so layer-2's softmax reads bits
// instead of re-reading 256 MB of adj.
__global__ __launch_bounds__(256) void att_softmax1_k(
    const int* __restrict__ adj, const float* __restrict__ e1,
    const float* __restrict__ e2, float* __restrict__ att,
    unsigned* __restrict__ bits)
{
  __shared__ float red[4];
  int i = blockIdx.x, t = threadIdx.x;
  const int4* arow = (const int4*)(adj + (size_t)i * 8192);
  unsigned* brow = bits + (size_t)i * 256;
  float e1i = e1[i];
  float4 vv[8];
  float s = 0.f;
#pragma unroll
  for (int it = 0; it < 8; ++it) {
    int j4 = t + it * 256;               // int4/float4 index
    int4 a4 = arow[j4];
    float4 ev = *(const float4*)(e2 + j4 * 4);
    // pack 4 bits -> butterfly-OR nibbles of 8 consecutive lanes into a word
    unsigned n = (unsigned)(a4.x > 0) | ((unsigned)(a4.y > 0) << 1)
               | ((unsigned)(a4.z > 0) << 2) | ((unsigned)(a4.w > 0) << 3);
    unsigned v = n << ((t & 7) * 4);
    v |= __shfl_xor(v, 1);
    v |= __shfl_xor(v, 2);
    v |= __shfl_xor(v, 4);
    if ((t & 7) == 0) brow[it * 32 + (t >> 3)] = v;
    float e, p0, p1, p2, p3;
    e = e1i + ev.x; e = e > 0.f ? e : LRELU_ALPHA * e; p0 = (a4.x > 0) ? __expf(e) : 0.f;
    e = e1i + ev.y; e = e > 0.f ? e : LRELU_ALPHA * e; p1 = (a4.y > 0) ? __expf(e) : 0.f;
    e = e1i + ev.z; e = e > 0.f ? e : LRELU_ALPHA * e; p2 = (a4.z > 0) ? __expf(e) : 0.f;
    e = e1i + ev.w; e = e > 0.f ? e : LRELU_ALPHA * e; p3 = (a4.w > 0) ? __expf(e) : 0.f;
    vv[it] = make_float4(p0, p1, p2, p3);
    s += (p0 + p1) + (p2 + p3);
  }
#pragma unroll
  for (int off = 32; off; off >>= 1) s += __shfl_xor(s, off);
  if ((t & 63) == 0) red[t >> 6] = s;
  __syncthreads();
  s = red[0] + red[1] + red[2] + red[3];
  float inv = 1.f / s;
  float4* orow = (float4*)(att + (size_t)i * 8192);
#pragma unroll
  for (int it = 0; it < 8; ++it) {
    float4 p = vv[it];
    p.x *= inv; p.y *= inv; p.z *= inv; p.w *= inv;
    orow[t + it * 256] = p;
  }
}

// ---------------- layer-2 masked softmax (bits mask) ----------------
__global__ __launch_bounds__(256) void att_softmax2_k(
    const unsigned* __restrict__ bits, const float* __restrict__ e1,
    const float* __restrict__ e2, float* __restrict__ att)
{
  __shared__ unsigned bw[256];
  __shared__ float red[4];
  int i = blockIdx.x, t = threadIdx.x;
  bw[t] = bits[(size_t)i * 256 + t];
  float e1i = e1[i];
  __syncthreads();
  float4 vv[8];
  float s = 0.f;
#pragma unroll
  for (int it = 0; it < 8; ++it) {
    int j4 = t + it * 256;
    float4 ev = *(const float4*)(e2 + j4 * 4);
    unsigned wb = bw[j4 >> 3];
    int b0 = (j4 & 7) * 4;
    float e, p0, p1, p2, p3;
    e = e1i + ev.x; e = e > 0.f ? e : LRELU_ALPHA * e; p0 = ((wb >> (b0 + 0)) & 1) ? __expf(e) : 0.f;
    e = e1i + ev.y; e = e > 0.f ? e : LRELU_ALPHA * e; p1 = ((wb >> (b0 + 1)) & 1) ? __expf(e) : 0.f;
    e = e1i + ev.z; e = e > 0.f ? e : LRELU_ALPHA * e; p2 = ((wb >> (b0 + 2)) & 1) ? __expf(e) : 0.f;
    e = e1i + ev.w; e = e > 0.f ? e : LRELU_ALPHA * e; p3 = ((wb >> (b0 + 3)) & 1) ? __expf(e) : 0.f;
    vv[it] = make_float4(p0, p1, p2, p3);
    s += (p0 + p1) + (p2 + p3);
  }
#pragma unroll
  for (int off = 32; off; off >>= 1) s += __shfl_xor(s, off);
  if ((t & 63) == 0) red[t >> 6] = s;
  __syncthreads();
  s = red[0] + red[1] + red[2] + red[3];
  float inv = 1.f / s;
  float4* orow = (float4*)(att + (size_t)i * 8192);
#pragma unroll
  for (int it = 0; it < 8; ++it) {
    float4 p = vv[it];
    p.x *= inv; p.y *= inv; p.z *= inv; p.w *= inv;
    orow[t + it * 256] = p;
  }
}

// ---------------- MFMA bf16 GEMM: C = epi(A_f32[M][K] @ BT_bf16[Nc][K]^T) ----------------
// R1-verbatim (fastest measured config). BM=64, BK=64, 4 waves.
// BN=64 (2x2 waves) or BN=16 (4x1 waves). EPI: 0=none,1=ELU.
// SPLITK>1: writes partials [split][M][ldc].
template<int BN, int SPLITK, int EPI>
__global__ __launch_bounds__(256) void gemm_mfma_k(
    const float* __restrict__ A, const unsigned short* __restrict__ BT,
    float* __restrict__ Cout, int M, int K, int ldc)
{
  constexpr int BM = 64, BK = 64;
  constexpr int WN = (BN == 64) ? 2 : 1;
  constexpr int WM = 4 / WN;
  constexpr int WROWS = BM / WM;   // 32 or 16
  constexpr int WCOLS = BN / WN;   // 32 or 16
  constexpr int FM = WROWS / 16;   // 2 or 1
  constexpr int FN = WCOLS / 16;   // 2 or 1
  __shared__ __align__(16) char As[BM * BK * 2];
  __shared__ __align__(16) char Bs[BN * BK * 2];
  int t = threadIdx.x;
  int row0 = blockIdx.x * BM;
  int col0 = blockIdx.y * BN;
  int ktiles = K / BK;
  int kt0 = blockIdx.z * (ktiles / SPLITK);
  int kt1 = kt0 + ktiles / SPLITK;
  int w = t >> 6, l = t & 63;
  int wm = w / WN, wn = w % WN;

  f32x4 acc[FM][FN] = {};

  int ar = t >> 2, aseg = t & 3;   // A staging: 64 rows x 4 segs of 16 floats
  int swzA = (ar & 7) << 4;

  for (int kt = kt0; kt < kt1; ++kt) {
    __syncthreads();
    { // stage A (fp32 -> bf16, swizzled)
      const float4* src = (const float4*)(A + (size_t)(row0 + ar) * K + kt * BK + aseg * 16);
      float4 v0 = src[0], v1 = src[1], v2 = src[2], v3 = src[3];
      u16x8 c0, c1;
      c0[0]=f2bf(v0.x); c0[1]=f2bf(v0.y); c0[2]=f2bf(v0.z); c0[3]=f2bf(v0.w);
      c0[4]=f2bf(v1.x); c0[5]=f2bf(v1.y); c0[6]=f2bf(v1.z); c0[7]=f2bf(v1.w);
      c1[0]=f2bf(v2.x); c1[1]=f2bf(v2.y); c1[2]=f2bf(v2.z); c1[3]=f2bf(v2.w);
      c1[4]=f2bf(v3.x); c1[5]=f2bf(v3.y); c1[6]=f2bf(v3.z); c1[7]=f2bf(v3.w);
      int base = ar * 128 + aseg * 32;
      *(u16x8*)(As + ((base) ^ swzA)) = c0;
      *(u16x8*)(As + ((base + 16) ^ swzA)) = c1;
    }
    if (BN == 64) { // stage B: 64 rows x 64 bf16
      int br = t >> 2, seg = t & 3;
      const u16x8* src = (const u16x8*)(BT + (size_t)(col0 + br) * K + kt * BK + seg * 16);
      u16x8 b0 = src[0], b1 = src[1];
      int base = br * 128 + seg * 32;
      int swz = (br & 7) << 4;
      *(u16x8*)(Bs + ((base) ^ swz)) = b0;
      *(u16x8*)(Bs + ((base + 16) ^ swz)) = b1;
    } else {        // BN==16: 16 rows x 64 bf16
      int br = t >> 4, seg = t & 15;
      const u16x4* src = (const u16x4*)(BT + (size_t)(col0 + br) * K + kt * BK + seg * 4);
      u16x4 b0 = src[0];
      int base = br * 128 + seg * 8;
      int swz = (br & 7) << 4;
      *(u16x4*)(Bs + (base ^ swz)) = b0;
    }
    __syncthreads();
#pragma unroll
    for (int kk = 0; kk < BK; kk += 32) {
      bf16x8 af[FM], bfr[FN];
      int kb = (kk + (l >> 4) * 8) * 2;
#pragma unroll
      for (int fm = 0; fm < FM; ++fm) {
        int r = wm * WROWS + fm * 16 + (l & 15);
        af[fm] = *(const bf16x8*)(As + ((r * 128 + kb) ^ ((r & 7) << 4)));
      }
#pragma unroll
      for (int fn = 0; fn < FN; ++fn) {
        int c = wn * WCOLS + fn * 16 + (l & 15);
        bfr[fn] = *(const bf16x8*)(Bs + ((c * 128 + kb) ^ ((c & 7) << 4)));
      }
#pragma unroll
      for (int fm = 0; fm < FM; ++fm)
#pragma unroll
        for (int fn = 0; fn < FN; ++fn)
          acc[fm][fn] = __builtin_amdgcn_mfma_f32_16x16x32_bf16(af[fm], bfr[fn], acc[fm][fn], 0, 0, 0);
    }
  }
  // epilogue: C/D layout col=lane&15, row=(lane>>4)*4+reg
#pragma unroll
  for (int fm = 0; fm < FM; ++fm) {
#pragma unroll
    for (int fn = 0; fn < FN; ++fn) {
#pragma unroll
      for (int r = 0; r < 4; ++r) {
        int grow = row0 + wm * WROWS + fm * 16 + (l >> 4) * 4 + r;
        int gcol = col0 + wn * WCOLS + fn * 16 + (l & 15);
        float v = acc[fm][fn][r];
        if (EPI == 1) v = v > 0.f ? v : expm1f(v);   // ELU alpha=1
        size_t idx = (SPLITK > 1)
          ? ((size_t)blockIdx.z * M + grow) * ldc + gcol
          : (size_t)grow * ldc + gcol;
        Cout[idx] = v;
      }
    }
  }
}

// ---------------- small GEMM: Wh2[M][16] = h1[M][256] @ W2[256][16] ----------------
__global__ __launch_bounds__(256) void gemm_small_k(
    const float* __restrict__ A, const float* __restrict__ B,
    float* __restrict__ C, int K, int Ncols)
{
  int t = threadIdx.x;
  int r = blockIdx.x * 16 + (t >> 4);
  int c = t & 15;
  const float* arow = A + (size_t)r * K;
  float acc = 0.f;
#pragma unroll 8
  for (int k = 0; k < K; ++k)
    acc = fmaf(arow[k], B[k * Ncols + c], acc);
  C[(size_t)r * Ncols + c] = acc;
}

// ---------------- split-K reduce + sigmoid ----------------
__global__ void reduce_sig_k(const float* __restrict__ part, float* __restrict__ out, int total)
{
  int i = blockIdx.x * 256 + threadIdx.x;
  if (i < total) {
    float s = part[i] + part[total + i] + part[2 * (size_t)total + i] + part[3 * (size_t)total + i];
    out[i] = 1.f / (1.f + __expf(-s));
  }
}

extern "C" void kernel_launch(void* const* d_in, const int* in_sizes, int n_in,
                              void* d_out, int out_size, void* d_ws, size_t ws_size,
                              hipStream_t stream)
{
  const float* x   = (const float*)d_in[0];
  const int*   adj = (const int*)d_in[1];
  const float* W1  = (const float*)d_in[2];
  const float* a1  = (const float*)d_in[3];
  const float* W2  = (const float*)d_in[4];
  const float* a2  = (const float*)d_in[5];

  float* out  = (float*)d_out;                 // [8192*16]
  float* h1   = out + 131072;                  // [8192*256]
  float* att1 = h1 + 2097152;                  // [8192*8192]
  float* att2 = att1 + 67108864;               // [8192*8192]

  float* ws = (float*)d_ws;
  float* wh1 = ws;                                            // 2097152 f
  unsigned short* bt1 = (unsigned short*)(wh1 + 2097152);     // 2097152 u16
  float* e1a = wh1 + 2097152 + 1048576;
  float* e2a = e1a + 8192;
  float* wh2 = e2a + 8192;                                    // 131072 f
  unsigned short* bt2 = (unsigned short*)(wh2 + 131072);      // 131072 u16
  float* e1b = wh2 + 131072 + 65536;
  float* e2b = e1b + 8192;
  float* part = e2b + 8192;                                   // 524288 f
  unsigned* bits = (unsigned*)(part + 524288);                // 2097152 u32

  // ---- layer 1 ----
  gemm_f32_k<<<dim3(64, 4), 256, 0, stream>>>(x, W1, wh1, 8192, 512, 256);
  calc_e_k<<<2048, 256, 0, stream>>>(wh1, a1, e1a, e2a, 256);
  transpose_bf16_k<<<dim3(8, 256), dim3(32, 8), 0, stream>>>(wh1, bt1, 8192, 256);
  att_softmax1_k<<<8192, 256, 0, stream>>>(adj, e1a, e2a, att1, bits);
  gemm_mfma_k<64, 1, 1><<<dim3(128, 4, 1), 256, 0, stream>>>(att1, bt1, h1, 8192, 8192, 256);

  // ---- layer 2 ----
  gemm_small_k<<<512, 256, 0, stream>>>(h1, W2, wh2, 256, 16);
  calc_e_k<<<2048, 256, 0, stream>>>(wh2, a2, e1b, e2b, 16);
  transpose_bf16_k<<<dim3(1, 256), dim3(32, 8), 0, stream>>>(wh2, bt2, 8192, 16);
  att_softmax2_k<<<8192, 256, 0, stream>>>(bits, e1b, e2b, att2);
  gemm_mfma_k<16, 4, 0><<<dim3(128, 1, 4), 256, 0, stream>>>(att2, bt2, part, 8192, 8192, 16);
  reduce_sig_k<<<512, 256, 0, stream>>>(part, out, 131072);
}

// Round 9
// 460.122 us; speedup vs baseline: 1.2258x; 1.0736x over previous
//
#include <hip/hip_runtime.h>
#include <hip/hip_bf16.h>

#define LRELU_ALPHA 0.2f

typedef __attribute__((ext_vector_type(8))) __bf16 bf16x8;
typedef __attribute__((ext_vector_type(4))) float f32x4;
typedef __attribute__((ext_vector_type(8))) unsigned short u16x8;
typedef __attribute__((ext_vector_type(4))) unsigned short u16x4;

__device__ __forceinline__ unsigned short f2bf(float f) {
  unsigned int u = __float_as_uint(f);
  u += 0x7fffu + ((u >> 16) & 1u);   // round-to-nearest-even
  return (unsigned short)(u >> 16);
}

// ---------------- fp32 tiled GEMM: wh1 = x @ W1 ----------------
__global__ __launch_bounds__(256) void gemm_f32_k(
    const float* __restrict__ A, const float* __restrict__ B,
    float* __restrict__ C, int M, int K, int Ncols)
{
  __shared__ float As[128][17];
  __shared__ float Bs[16][65];
  int t = threadIdx.x;
  int row0 = blockIdx.x * 128;
  int col0 = blockIdx.y * 64;
  int ty = t >> 4, tx = t & 15;
  float acc[8][4];
#pragma unroll
  for (int i = 0; i < 8; ++i)
#pragma unroll
    for (int j = 0; j < 4; ++j) acc[i][j] = 0.f;

  for (int kt = 0; kt < K; kt += 16) {
    __syncthreads();
    {
      int r = t >> 1, h = t & 1;
      const float4* src = (const float4*)(A + (size_t)(row0 + r) * K + kt + h * 8);
      float4 v0 = src[0], v1 = src[1];
      float* dst = &As[r][h * 8];
      dst[0]=v0.x; dst[1]=v0.y; dst[2]=v0.z; dst[3]=v0.w;
      dst[4]=v1.x; dst[5]=v1.y; dst[6]=v1.z; dst[7]=v1.w;
    }
    {
      int kr = t >> 4, seg = t & 15;
      const float4* src = (const float4*)(B + (size_t)(kt + kr) * Ncols + col0 + seg * 4);
      float4 v = src[0];
      float* dst = &Bs[kr][seg * 4];
      dst[0]=v.x; dst[1]=v.y; dst[2]=v.z; dst[3]=v.w;
    }
    __syncthreads();
#pragma unroll
    for (int k = 0; k < 16; ++k) {
      float bb[4];
#pragma unroll
      for (int j = 0; j < 4; ++j) bb[j] = Bs[k][tx * 4 + j];
#pragma unroll
      for (int i = 0; i < 8; ++i) {
        float aa = As[ty * 8 + i][k];
#pragma unroll
        for (int j = 0; j < 4; ++j) acc[i][j] = fmaf(aa, bb[j], acc[i][j]);
      }
    }
  }
#pragma unroll
  for (int i = 0; i < 8; ++i) {
    float4 v = make_float4(acc[i][0], acc[i][1], acc[i][2], acc[i][3]);
    *(float4*)(C + (size_t)(row0 + ty * 8 + i) * Ncols + col0 + tx * 4) = v;
  }
}

// ---------------- e1/e2 vectors: wave per row ----------------
__global__ __launch_bounds__(256) void calc_e_k(
    const float* __restrict__ Wh, const float* __restrict__ a,
    float* __restrict__ e1, float* __restrict__ e2, int F)
{
  int row = blockIdx.x * 4 + (threadIdx.x >> 6);
  int l = threadIdx.x & 63;
  const float* r = Wh + (size_t)row * F;
  float s1 = 0.f, s2 = 0.f;
  for (int f = l; f < F; f += 64) {
    float v = r[f];
    s1 += v * a[f];
    s2 += v * a[F + f];
  }
#pragma unroll
  for (int off = 32; off; off >>= 1) {
    s1 += __shfl_down(s1, off);
    s2 += __shfl_down(s2, off);
  }
  if (l == 0) { e1[row] = s1; e2[row] = s2; }
}

// ---------------- transpose + fp32->bf16: out[c][r] = bf16(in[r][c]) ----------------
__global__ void transpose_bf16_k(const float* __restrict__ in, unsigned short* __restrict__ out,
                                 int R, int Cc)
{
  __shared__ float tile[32][33];
  int tx = threadIdx.x, ty = threadIdx.y;
  int c0 = blockIdx.x * 32, r0 = blockIdx.y * 32;
  int c = c0 + tx;
  if (c < Cc) {
    for (int i = ty; i < 32; i += 8)
      tile[i][tx] = in[(size_t)(r0 + i) * Cc + c];
  }
  __syncthreads();
  int r = r0 + tx;
  for (int i = ty; i < 32; i += 8) {
    int cc = c0 + i;
    if (cc < Cc)
      out[(size_t)cc * R + r] = f2bf(tile[tx][i]);
  }
}

// ---------------- layer-1 masked softmax + inline adj bit-pack ----------------
__global__ __launch_bounds__(256) void att_softmax1_k(
    const int* __restrict__ adj, const float* __restrict__ e1,
    const float* __restrict__ e2, float* __restrict__ att,
    unsigned* __restrict__ bits)
{
  __shared__ float red[4];
  int i = blockIdx.x, t = threadIdx.x;
  const int4* arow = (const int4*)(adj + (size_t)i * 8192);
  unsigned* brow = bits + (size_t)i * 256;
  float e1i = e1[i];
  float4 vv[8];
  float s = 0.f;
#pragma unroll
  for (int it = 0; it < 8; ++it) {
    int j4 = t + it * 256;               // int4/float4 index
    int4 a4 = arow[j4];
    float4 ev = *(const float4*)(e2 + j4 * 4);
    unsigned n = (unsigned)(a4.x > 0) | ((unsigned)(a4.y > 0) << 1)
               | ((unsigned)(a4.z > 0) << 2) | ((unsigned)(a4.w > 0) << 3);
    unsigned v = n << ((t & 7) * 4);
    v |= __shfl_xor(v, 1);
    v |= __shfl_xor(v, 2);
    v |= __shfl_xor(v, 4);
    if ((t & 7) == 0) brow[it * 32 + (t >> 3)] = v;
    float e, p0, p1, p2, p3;
    e = e1i + ev.x; e = e > 0.f ? e : LRELU_ALPHA * e; p0 = (a4.x > 0) ? __expf(e) : 0.f;
    e = e1i + ev.y; e = e > 0.f ? e : LRELU_ALPHA * e; p1 = (a4.y > 0) ? __expf(e) : 0.f;
    e = e1i + ev.z; e = e > 0.f ? e : LRELU_ALPHA * e; p2 = (a4.z > 0) ? __expf(e) : 0.f;
    e = e1i + ev.w; e = e > 0.f ? e : LRELU_ALPHA * e; p3 = (a4.w > 0) ? __expf(e) : 0.f;
    vv[it] = make_float4(p0, p1, p2, p3);
    s += (p0 + p1) + (p2 + p3);
  }
#pragma unroll
  for (int off = 32; off; off >>= 1) s += __shfl_xor(s, off);
  if ((t & 63) == 0) red[t >> 6] = s;
  __syncthreads();
  s = red[0] + red[1] + red[2] + red[3];
  float inv = 1.f / s;
  float4* orow = (float4*)(att + (size_t)i * 8192);
#pragma unroll
  for (int it = 0; it < 8; ++it) {
    float4 p = vv[it];
    p.x *= inv; p.y *= inv; p.z *= inv; p.w *= inv;
    orow[t + it * 256] = p;
  }
}

// ---------------- layer-2 masked softmax (bits mask) ----------------
__global__ __launch_bounds__(256) void att_softmax2_k(
    const unsigned* __restrict__ bits, const float* __restrict__ e1,
    const float* __restrict__ e2, float* __restrict__ att)
{
  __shared__ unsigned bw[256];
  __shared__ float red[4];
  int i = blockIdx.x, t = threadIdx.x;
  bw[t] = bits[(size_t)i * 256 + t];
  float e1i = e1[i];
  __syncthreads();
  float4 vv[8];
  float s = 0.f;
#pragma unroll
  for (int it = 0; it < 8; ++it) {
    int j4 = t + it * 256;
    float4 ev = *(const float4*)(e2 + j4 * 4);
    unsigned wb = bw[j4 >> 3];
    int b0 = (j4 & 7) * 4;
    float e, p0, p1, p2, p3;
    e = e1i + ev.x; e = e > 0.f ? e : LRELU_ALPHA * e; p0 = ((wb >> (b0 + 0)) & 1) ? __expf(e) : 0.f;
    e = e1i + ev.y; e = e > 0.f ? e : LRELU_ALPHA * e; p1 = ((wb >> (b0 + 1)) & 1) ? __expf(e) : 0.f;
    e = e1i + ev.z; e = e > 0.f ? e : LRELU_ALPHA * e; p2 = ((wb >> (b0 + 2)) & 1) ? __expf(e) : 0.f;
    e = e1i + ev.w; e = e > 0.f ? e : LRELU_ALPHA * e; p3 = ((wb >> (b0 + 3)) & 1) ? __expf(e) : 0.f;
    vv[it] = make_float4(p0, p1, p2, p3);
    s += (p0 + p1) + (p2 + p3);
  }
#pragma unroll
  for (int off = 32; off; off >>= 1) s += __shfl_xor(s, off);
  if ((t & 63) == 0) red[t >> 6] = s;
  __syncthreads();
  s = red[0] + red[1] + red[2] + red[3];
  float inv = 1.f / s;
  float4* orow = (float4*)(att + (size_t)i * 8192);
#pragma unroll
  for (int it = 0; it < 8; ++it) {
    float4 p = vv[it];
    p.x *= inv; p.y *= inv; p.z *= inv; p.w *= inv;
    orow[t + it * 256] = p;
  }
}

// ---------------- MFMA bf16 GEMM: C = A_f32[M][K] @ BT_bf16[Nc][K]^T ----------------
// R1-verbatim body. BM=64, BK=64, 4 waves. SPLITK>1 writes partials [z][M][ldc].
template<int BN, int SPLITK, int EPI>
__global__ __launch_bounds__(256) void gemm_mfma_k(
    const float* __restrict__ A, const unsigned short* __restrict__ BT,
    float* __restrict__ Cout, int M, int K, int ldc)
{
  constexpr int BM = 64, BK = 64;
  constexpr int WN = (BN == 64) ? 2 : 1;
  constexpr int WM = 4 / WN;
  constexpr int WROWS = BM / WM;
  constexpr int WCOLS = BN / WN;
  constexpr int FM = WROWS / 16;
  constexpr int FN = WCOLS / 16;
  __shared__ __align__(16) char As[BM * BK * 2];
  __shared__ __align__(16) char Bs[BN * BK * 2];
  int t = threadIdx.x;
  int row0 = blockIdx.x * BM;
  int col0 = blockIdx.y * BN;
  int ktiles = K / BK;
  int kt0 = blockIdx.z * (ktiles / SPLITK);
  int kt1 = kt0 + ktiles / SPLITK;
  int w = t >> 6, l = t & 63;
  int wm = w / WN, wn = w % WN;

  f32x4 acc[FM][FN] = {};

  int ar = t >> 2, aseg = t & 3;
  int swzA = (ar & 7) << 4;

  for (int kt = kt0; kt < kt1; ++kt) {
    __syncthreads();
    {
      const float4* src = (const float4*)(A + (size_t)(row0 + ar) * K + kt * BK + aseg * 16);
      float4 v0 = src[0], v1 = src[1], v2 = src[2], v3 = src[3];
      u16x8 c0, c1;
      c0[0]=f2bf(v0.x); c0[1]=f2bf(v0.y); c0[2]=f2bf(v0.z); c0[3]=f2bf(v0.w);
      c0[4]=f2bf(v1.x); c0[5]=f2bf(v1.y); c0[6]=f2bf(v1.z); c0[7]=f2bf(v1.w);
      c1[0]=f2bf(v2.x); c1[1]=f2bf(v2.y); c1[2]=f2bf(v2.z); c1[3]=f2bf(v2.w);
      c1[4]=f2bf(v3.x); c1[5]=f2bf(v3.y); c1[6]=f2bf(v3.z); c1[7]=f2bf(v3.w);
      int base = ar * 128 + aseg * 32;
      *(u16x8*)(As + ((base) ^ swzA)) = c0;
      *(u16x8*)(As + ((base + 16) ^ swzA)) = c1;
    }
    if (BN == 64) {
      int br = t >> 2, seg = t & 3;
      const u16x8* src = (const u16x8*)(BT + (size_t)(col0 + br) * K + kt * BK + seg * 16);
      u16x8 b0 = src[0], b1 = src[1];
      int base = br * 128 + seg * 32;
      int swz = (br & 7) << 4;
      *(u16x8*)(Bs + ((base) ^ swz)) = b0;
      *(u16x8*)(Bs + ((base + 16) ^ swz)) = b1;
    } else {
      int br = t >> 4, seg = t & 15;
      const u16x4* src = (const u16x4*)(BT + (size_t)(col0 + br) * K + kt * BK + seg * 4);
      u16x4 b0 = src[0];
      int base = br * 128 + seg * 8;
      int swz = (br & 7) << 4;
      *(u16x4*)(Bs + (base ^ swz)) = b0;
    }
    __syncthreads();
#pragma unroll
    for (int kk = 0; kk < BK; kk += 32) {
      bf16x8 af[FM], bfr[FN];
      int kb = (kk + (l >> 4) * 8) * 2;
#pragma unroll
      for (int fm = 0; fm < FM; ++fm) {
        int r = wm * WROWS + fm * 16 + (l & 15);
        af[fm] = *(const bf16x8*)(As + ((r * 128 + kb) ^ ((r & 7) << 4)));
      }
#pragma unroll
      for (int fn = 0; fn < FN; ++fn) {
        int c = wn * WCOLS + fn * 16 + (l & 15);
        bfr[fn] = *(const bf16x8*)(Bs + ((c * 128 + kb) ^ ((c & 7) << 4)));
      }
#pragma unroll
      for (int fm = 0; fm < FM; ++fm)
#pragma unroll
        for (int fn = 0; fn < FN; ++fn)
          acc[fm][fn] = __builtin_amdgcn_mfma_f32_16x16x32_bf16(af[fm], bfr[fn], acc[fm][fn], 0, 0, 0);
    }
  }
#pragma unroll
  for (int fm = 0; fm < FM; ++fm) {
#pragma unroll
    for (int fn = 0; fn < FN; ++fn) {
#pragma unroll
      for (int r = 0; r < 4; ++r) {
        int grow = row0 + wm * WROWS + fm * 16 + (l >> 4) * 4 + r;
        int gcol = col0 + wn * WCOLS + fn * 16 + (l & 15);
        float v = acc[fm][fn][r];
        if (EPI == 1) v = v > 0.f ? v : expm1f(v);
        size_t idx = (SPLITK > 1)
          ? ((size_t)blockIdx.z * M + grow) * ldc + gcol
          : (size_t)grow * ldc + gcol;
        Cout[idx] = v;
      }
    }
  }
}

// ---------------- small GEMM: Wh2[M][16] = h1[M][256] @ W2[256][16] ----------------
__global__ __launch_bounds__(256) void gemm_small_k(
    const float* __restrict__ A, const float* __restrict__ B,
    float* __restrict__ C, int K, int Ncols)
{
  int t = threadIdx.x;
  int r = blockIdx.x * 16 + (t >> 4);
  int c = t & 15;
  const float* arow = A + (size_t)r * K;
  float acc = 0.f;
#pragma unroll 8
  for (int k = 0; k < K; ++k)
    acc = fmaf(arow[k], B[k * Ncols + c], acc);
  C[(size_t)r * Ncols + c] = acc;
}

// ---------------- split-K reduce + ELU (gemm1 epilogue) ----------------
__global__ void reduce_elu_k(const float* __restrict__ part, float* __restrict__ out, int total)
{
  int i = blockIdx.x * 256 + threadIdx.x;
  if (i < total) {
    float s = (part[i] + part[total + i]) + (part[2 * (size_t)total + i] + part[3 * (size_t)total + i]);
    out[i] = s > 0.f ? s : expm1f(s);
  }
}

// ---------------- split-K reduce + sigmoid ----------------
__global__ void reduce_sig_k(const float* __restrict__ part, float* __restrict__ out, int total)
{
  int i = blockIdx.x * 256 + threadIdx.x;
  if (i < total) {
    float s = part[i] + part[total + i] + part[2 * (size_t)total + i] + part[3 * (size_t)total + i];
    out[i] = 1.f / (1.f + __expf(-s));
  }
}

extern "C" void kernel_launch(void* const* d_in, const int* in_sizes, int n_in,
                              void* d_out, int out_size, void* d_ws, size_t ws_size,
                              hipStream_t stream)
{
  const float* x   = (const float*)d_in[0];
  const int*   adj = (const int*)d_in[1];
  const float* W1  = (const float*)d_in[2];
  const float* a1  = (const float*)d_in[3];
  const float* W2  = (const float*)d_in[4];
  const float* a2  = (const float*)d_in[5];

  float* out  = (float*)d_out;                 // [8192*16]
  float* h1   = out + 131072;                  // [8192*256]
  float* att1 = h1 + 2097152;                  // [8192*8192]
  float* att2 = att1 + 67108864;               // [8192*8192]

  float* ws = (float*)d_ws;
  float* wh1 = ws;                                            // 2097152 f
  unsigned short* bt1 = (unsigned short*)(wh1 + 2097152);     // 2097152 u16
  float* e1a = wh1 + 2097152 + 1048576;
  float* e2a = e1a + 8192;
  float* wh2 = e2a + 8192;                                    // 131072 f
  unsigned short* bt2 = (unsigned short*)(wh2 + 131072);      // 131072 u16
  float* e1b = wh2 + 131072 + 65536;
  float* e2b = e1b + 8192;
  float* part2 = e2b + 8192;                                  // 524288 f
  unsigned* bits = (unsigned*)(part2 + 524288);               // 2097152 u32
  float* part1 = (float*)(bits + 2097152);                    // 4*2097152 f

  // ---- layer 1 ----
  gemm_f32_k<<<dim3(64, 4), 256, 0, stream>>>(x, W1, wh1, 8192, 512, 256);
  calc_e_k<<<2048, 256, 0, stream>>>(wh1, a1, e1a, e2a, 256);
  transpose_bf16_k<<<dim3(8, 256), dim3(32, 8), 0, stream>>>(wh1, bt1, 8192, 256);
  att_softmax1_k<<<8192, 256, 0, stream>>>(adj, e1a, e2a, att1, bits);
  gemm_mfma_k<64, 4, 0><<<dim3(128, 4, 4), 256, 0, stream>>>(att1, bt1, part1, 8192, 8192, 256);
  reduce_elu_k<<<8192, 256, 0, stream>>>(part1, h1, 2097152);

  // ---- layer 2 ----
  gemm_small_k<<<512, 256, 0, stream>>>(h1, W2, wh2, 256, 16);
  calc_e_k<<<2048, 256, 0, stream>>>(wh2, a2, e1b, e2b, 16);
  transpose_bf16_k<<<dim3(1, 256), dim3(32, 8), 0, stream>>>(wh2, bt2, 8192, 16);
  att_softmax2_k<<<8192, 256, 0, stream>>>(bits, e1b, e2b, att2);
  gemm_mfma_k<16, 4, 0><<<dim3(128, 1, 4), 256, 0, stream>>>(att2, bt2, part2, 8192, 8192, 16);
  reduce_sig_k<<<512, 256, 0, stream>>>(part2, out, 131072);
}